// Round 2
// baseline (532.774 us; speedup 1.0000x reference)
//
#include <hip/hip_runtime.h>
#include <stdint.h>

#define NROWS 2048
#define NCOLS 50257
#define HALVES 2          // blocks per row
#define SCALE 30.0f
// SCALE * log2(e): exp(30*x) == exp2(K2*x)
#define K2 43.28085122666891f

typedef float v4f __attribute__((ext_vector_type(4)));

// v_exp_f32 computes 2^x. Avoid __exp2f (glibc macro collision in this TU).
static __device__ __forceinline__ float fexp2(float x) {
    return __builtin_amdgcn_exp2f(x);
}

// Stage 1: two blocks per row, each sums exp2(K2*x) over half the row's
// vector range. Partial sum -> psum[blockIdx.x]. No atomics.
__global__ __launch_bounds__(256) void amsoftmax_partial_kernel(
    const float* __restrict__ score,
    float* __restrict__ psum) {
    const int row = blockIdx.x >> 1;
    const int half = blockIdx.x & 1;
    const int tid = threadIdx.x;
    const float* __restrict__ r = score + (size_t)row * NCOLS;

    // Row base is only 4B-aligned (NCOLS odd). Peel to 16B alignment.
    const uintptr_t addr = (uintptr_t)r;
    const int mis = (int)(((16u - (addr & 15u)) & 15u) >> 2);
    const int nvec = (NCOLS - mis) >> 2;
    const float* __restrict__ rb = r + mis;

    const int lo = half ? (nvec >> 1) : 0;
    const int hi = half ? nvec : (nvec >> 1);

    float a0 = 0.0f, a1 = 0.0f, a2 = 0.0f, a3 = 0.0f;

    // Half 0 takes the misaligned head scalars, half 1 the tail scalars.
    if (!half) {
        for (int j = tid; j < mis; j += 256) a0 += fexp2(K2 * r[j]);
    } else {
        for (int k = mis + (nvec << 2) + tid; k < NCOLS; k += 256)
            a1 += fexp2(K2 * r[k]);
    }

    // x4 unroll, 4 independent dwordx4 loads in flight per wave.
    int j = lo + tid;
    for (; j + 768 < hi; j += 1024) {
        v4f v0 = *(const v4f*)(rb + 4 * (size_t)j);
        v4f v1 = *(const v4f*)(rb + 4 * (size_t)(j + 256));
        v4f v2 = *(const v4f*)(rb + 4 * (size_t)(j + 512));
        v4f v3 = *(const v4f*)(rb + 4 * (size_t)(j + 768));
        a0 += fexp2(K2 * v0.x) + fexp2(K2 * v0.y) +
              fexp2(K2 * v0.z) + fexp2(K2 * v0.w);
        a1 += fexp2(K2 * v1.x) + fexp2(K2 * v1.y) +
              fexp2(K2 * v1.z) + fexp2(K2 * v1.w);
        a2 += fexp2(K2 * v2.x) + fexp2(K2 * v2.y) +
              fexp2(K2 * v2.z) + fexp2(K2 * v2.w);
        a3 += fexp2(K2 * v3.x) + fexp2(K2 * v3.y) +
              fexp2(K2 * v3.z) + fexp2(K2 * v3.w);
    }
    for (; j < hi; j += 256) {
        v4f v = *(const v4f*)(rb + 4 * (size_t)j);
        a0 += fexp2(K2 * v.x) + fexp2(K2 * v.y) +
              fexp2(K2 * v.z) + fexp2(K2 * v.w);
    }

    float acc = (a0 + a1) + (a2 + a3);
    for (int off = 32; off > 0; off >>= 1) acc += __shfl_down(acc, off);
    __shared__ float wsum[4];
    if ((tid & 63) == 0) wsum[tid >> 6] = acc;
    __syncthreads();
    if (tid == 0) {
        psum[blockIdx.x] = wsum[0] + wsum[1] + wsum[2] + wsum[3];
    }
}

// Stage 2: one block. Per row: combine the two halves, apply the margin
// logic, accumulate -L/NROWS, write out[0].
__global__ __launch_bounds__(256) void amsoftmax_finalize_kernel(
    const float* __restrict__ score,
    const int* __restrict__ labels,
    const float* __restrict__ psum,
    float* __restrict__ out) {
    const int tid = threadIdx.x;
    float s = 0.0f;
    for (int row = tid; row < NROWS; row += 256) {
        const float total = psum[2 * row] + psum[2 * row + 1];
        const int lab = labels[row];
        const float target = score[(size_t)row * NCOLS + lab];
        const float margin = lab ? 0.4f : 0.1f;
        const float num = SCALE * (target - margin);
        const float excl = total - fexp2(K2 * target);
        const float denom = __expf(num) + excl;
        const float L = num - __logf(denom);
        s += L;
    }
    for (int off = 32; off > 0; off >>= 1) s += __shfl_down(s, off);
    __shared__ float wsum[4];
    if ((tid & 63) == 0) wsum[tid >> 6] = s;
    __syncthreads();
    if (tid == 0) {
        out[0] = -(wsum[0] + wsum[1] + wsum[2] + wsum[3]) *
                 (1.0f / (float)NROWS);
    }
}

extern "C" void kernel_launch(void* const* d_in, const int* in_sizes, int n_in,
                              void* d_out, int out_size, void* d_ws, size_t ws_size,
                              hipStream_t stream) {
    const float* score = (const float*)d_in[0];
    const int* labels = (const int*)d_in[1];
    float* out = (float*)d_out;
    float* psum = (float*)d_ws;  // NROWS*HALVES floats

    amsoftmax_partial_kernel<<<NROWS * HALVES, 256, 0, stream>>>(score, psum);
    amsoftmax_finalize_kernel<<<1, 256, 0, stream>>>(score, labels, psum, out);
}